// Round 7
// baseline (337.438 us; speedup 1.0000x reference)
//
#include <hip/hip_runtime.h>

#define B_   8
#define CIN  512
#define NN_  4096
#define DD   256
#define KK   2048
#define KSPLIT 4
#define KPER (KK / KSPLIT)   // 512
#define NG   (B_ * NN_)      // 32768 total samples

typedef _Float16 f16x8 __attribute__((ext_vector_type(8)));
typedef _Float16 f16x4 __attribute__((ext_vector_type(4)));
typedef float    f32x16 __attribute__((ext_vector_type(16)));

#define MFMA16 __builtin_amdgcn_mfma_f32_32x32x16_f16

// async global->LDS, 16B per lane; LDS dest is wave-uniform base + lane*16
#define GLDS16(gp, lp) __builtin_amdgcn_global_load_lds( \
    (const __attribute__((address_space(1))) void*)(gp), \
    (__attribute__((address_space(3))) void*)(lp), 16, 0, 0)

// ---------- kernel 1: esq[k] = sum_d emb[k,d]^2 ; emit emb hi/lo f16 ----------
__global__ __launch_bounds__(256) void k_esq(const float* __restrict__ emb,
                                             float* __restrict__ esq,
                                             _Float16* __restrict__ emb_h,
                                             _Float16* __restrict__ emb_l) {
  int t = threadIdx.x;
  int lane = t & 63;
  int k = blockIdx.x * 4 + (t >> 6);
  float4 v = *(const float4*)&emb[(size_t)k * DD + 4 * lane];
  float s = v.x * v.x + v.y * v.y + v.z * v.z + v.w * v.w;
  f16x4 h, l;
  float* vp = (float*)&v;
#pragma unroll
  for (int i = 0; i < 4; i++) {
    _Float16 hh = (_Float16)vp[i];
    h[i] = hh;
    l[i] = (_Float16)(vp[i] - (float)hh);
  }
  *(f16x4*)&emb_h[(size_t)k * DD + 4 * lane] = h;
  *(f16x4*)&emb_l[(size_t)k * DD + 4 * lane] = l;
  for (int off = 32; off > 0; off >>= 1) s += __shfl_down(s, off, 64);
  if (lane == 0) esq[k] = s;
}

// ---------- kernel 2: MFMA split-f16 conv: zeT_{h,l}[b,n,d] = sum_c W[d,c] z[b,c,n] ----------
__global__ __launch_bounds__(256) void k_ze(const float* __restrict__ W,
                                            const float* __restrict__ z,
                                            _Float16* __restrict__ zeT_h,
                                            _Float16* __restrict__ zeT_l) {
  // Ah[2][128][32] f16 @0 (16384), Al @16384, Zs[2][32][128] f32 @32768 (32768)
  // epilogue overlay: Eh[128][132] f16 @0 (33792), El @33792 -> 67584 total
  __shared__ __align__(16) char sm[67584];
  const int t = threadIdx.x;
  const int w = t >> 6, lane = t & 63;
  const int lr = lane & 31, lh = lane >> 5;
  const int wm = w & 1, wn = w >> 1;
  const int swz = (lr >> 1) & 3;
  const int b = blockIdx.z, d0 = blockIdx.y * 128, n0 = blockIdx.x * 128;
  const float* zb = z + (size_t)b * CIN * NN_ + n0;

  _Float16* Ah = (_Float16*)sm;             // [2][128][32] swizzled 16B chunks
  _Float16* Al = (_Float16*)(sm + 16384);
  float*    Zs = (float*)(sm + 32768);      // [2][32][128] plain

  auto stageA = [&](int buf, int c0) {
#pragma unroll
    for (int i = 0; i < 4; i++) {
      int fid = i * 256 + t;
      int d = fid >> 3, q8 = fid & 7;        // global 8B chunk 0..7
      float4 v = *(const float4*)&W[(size_t)(d0 + d) * CIN + c0 + 4 * q8];
      float* vp = (float*)&v;
      f16x4 h, l;
#pragma unroll
      for (int e = 0; e < 4; e++) {
        _Float16 hh = (_Float16)vp[e];
        h[e] = hh;
        l[e] = (_Float16)(vp[e] - (float)hh);
      }
      int p16 = (q8 >> 1) ^ ((d >> 1) & 3);  // swizzled 16B chunk
      int off = (buf * 128 + d) * 32 + p16 * 8 + (q8 & 1) * 4;
      *(f16x4*)&Ah[off] = h;
      *(f16x4*)&Al[off] = l;
    }
  };
  auto stageZ = [&](int buf, int c0) {
#pragma unroll
    for (int i = 0; i < 4; i++) {
      int r = 8 * w + 2 * i;
      float* lbase = Zs + (size_t)buf * 4096 + r * 128;
      const float* gp = zb + (size_t)(c0 + r + lh) * NN_ + 4 * lr;
      GLDS16(gp, lbase);
    }
  };

  f32x16 acc[2][2];
#pragma unroll
  for (int mt = 0; mt < 2; mt++)
#pragma unroll
    for (int nt = 0; nt < 2; nt++)
#pragma unroll
      for (int i = 0; i < 16; i++) acc[mt][nt][i] = 0.0f;

  stageA(0, 0);
  stageZ(0, 0);
  int buf = 0;
  for (int c0 = 0; c0 < CIN; c0 += 32) {
    __syncthreads();
    if (c0 + 32 < CIN) { stageA(buf ^ 1, c0 + 32); stageZ(buf ^ 1, c0 + 32); }
    const _Float16* AhB = Ah + (size_t)buf * 128 * 32;
    const _Float16* AlB = Al + (size_t)buf * 128 * 32;
    const float*    ZsB = Zs + (size_t)buf * 4096;
#pragma unroll
    for (int s = 0; s < 2; s++) {
      const int cbase = 16 * s + 8 * lh;        // logical c offset (Zs reads)
      const int pa = (2 * s + lh) ^ swz;        // swizzled chunk (A reads)
      const int aoff = pa * 8;
      f16x8 ah0 = *(const f16x8*)&AhB[(wm * 64 + lr) * 32 + aoff];
      f16x8 ah1 = *(const f16x8*)&AhB[(wm * 64 + 32 + lr) * 32 + aoff];
      f16x8 al0 = *(const f16x8*)&AlB[(wm * 64 + lr) * 32 + aoff];
      f16x8 al1 = *(const f16x8*)&AlB[(wm * 64 + 32 + lr) * 32 + aoff];
      f16x8 bh0, bl0, bh1, bl1;
#pragma unroll
      for (int j = 0; j < 8; j++) {
        float x0 = ZsB[(cbase + j) * 128 + wn * 64 + lr];
        float x1 = ZsB[(cbase + j) * 128 + wn * 64 + 32 + lr];
        _Float16 h0 = (_Float16)x0;
        bh0[j] = h0;
        bl0[j] = (_Float16)(x0 - (float)h0);
        _Float16 h1 = (_Float16)x1;
        bh1[j] = h1;
        bl1[j] = (_Float16)(x1 - (float)h1);
      }
      acc[0][0] = MFMA16(ah0, bh0, acc[0][0], 0, 0, 0);
      acc[0][1] = MFMA16(ah0, bh1, acc[0][1], 0, 0, 0);
      acc[1][0] = MFMA16(ah1, bh0, acc[1][0], 0, 0, 0);
      acc[1][1] = MFMA16(ah1, bh1, acc[1][1], 0, 0, 0);
      acc[0][0] = MFMA16(ah0, bl0, acc[0][0], 0, 0, 0);
      acc[0][1] = MFMA16(ah0, bl1, acc[0][1], 0, 0, 0);
      acc[1][0] = MFMA16(ah1, bl0, acc[1][0], 0, 0, 0);
      acc[1][1] = MFMA16(ah1, bl1, acc[1][1], 0, 0, 0);
      acc[0][0] = MFMA16(al0, bh0, acc[0][0], 0, 0, 0);
      acc[0][1] = MFMA16(al0, bh1, acc[0][1], 0, 0, 0);
      acc[1][0] = MFMA16(al1, bh0, acc[1][0], 0, 0, 0);
      acc[1][1] = MFMA16(al1, bh1, acc[1][1], 0, 0, 0);
    }
    buf ^= 1;
  }

  __syncthreads();
  _Float16* Eh = (_Float16*)sm;             // [128][132]
  _Float16* El = (_Float16*)(sm + 33792);
#pragma unroll
  for (int mt = 0; mt < 2; mt++)
#pragma unroll
    for (int nt = 0; nt < 2; nt++) {
      int n_l = wn * 64 + nt * 32 + lr;
#pragma unroll
      for (int g = 0; g < 4; g++) {
        int d_l = wm * 64 + mt * 32 + 8 * g + 4 * lh;
        f16x4 h, l;
#pragma unroll
        for (int e = 0; e < 4; e++) {
          float x = acc[mt][nt][4 * g + e];
          _Float16 hh = (_Float16)x;
          h[e] = hh;
          l[e] = (_Float16)(x - (float)hh);
        }
        *(f16x4*)&Eh[n_l * 132 + d_l] = h;
        *(f16x4*)&El[n_l * 132 + d_l] = l;
      }
    }
  __syncthreads();
  _Float16* gh = zeT_h + ((size_t)b * NN_ + n0) * DD + d0;
  _Float16* gl = zeT_l + ((size_t)b * NN_ + n0) * DD + d0;
#pragma unroll
  for (int i = 0; i < 16; i++) {
    int n = i * 8 + w * 2 + lh;
    int d = 4 * lr;
    *(f16x4*)&gh[(size_t)n * DD + d] = *(const f16x4*)&Eh[n * 132 + d];
    *(f16x4*)&gl[(size_t)n * DD + d] = *(const f16x4*)&El[n * 132 + d];
  }
}

// ---------- kernel 3: MFMA split-f16 partial argmin over one K-split ----------
// A (emb) via swizzled LDS; B (zeT) fed DIRECTLY global->VGPR, double-buffered
__global__ __launch_bounds__(256) void k_argmin(const _Float16* __restrict__ emb_h,
                                                const _Float16* __restrict__ emb_l,
                                                const _Float16* __restrict__ zeT_h,
                                                const _Float16* __restrict__ zeT_l,
                                                const float* __restrict__ esq,
                                                float* __restrict__ pval,
                                                int* __restrict__ pidx) {
  // EH[2][128][32] @0 (16384), EL @16384; esqs @32768; pv @34816; pi @35840
  __shared__ __align__(16) char sm[36864];
  const int t = threadIdx.x;
  const int w = t >> 6, lane = t & 63;
  const int lr = lane & 31, lh = lane >> 5;
  const int wm = w & 1, wn = w >> 1;
  const int swz = (lr >> 1) & 3;
  const int b = blockIdx.y, n0 = blockIdx.x * 128, ks = blockIdx.z;
  const int kbase = ks * KPER;

  float* esqs = (float*)(sm + 32768);
  *(float2*)&esqs[2 * t] = *(const float2*)&esq[kbase + 2 * t];

  const _Float16* zb_h = zeT_h + ((size_t)b * NN_ + n0) * DD;
  const _Float16* zb_l = zeT_l + ((size_t)b * NN_ + n0) * DD;
  // per-lane B base pointers: rows wn*64+lr (+32), k-chunk 8*lh
  const _Float16* pB0h = zb_h + (size_t)(wn * 64 + lr) * DD + 8 * lh;
  const _Float16* pB1h = pB0h + 32 * DD;
  const _Float16* pB0l = zb_l + (size_t)(wn * 64 + lr) * DD + 8 * lh;
  const _Float16* pB1l = pB0l + 32 * DD;

  auto stageE = [&](int buf, int kt, int dc) {
    const int k0 = kbase + kt * 128;
    const int q = lane & 3, rr = lane >> 2;
    const int g = q ^ ((rr >> 1) & 3);   // swizzled global 16B chunk
    const int rb0 = 32 * w;
#pragma unroll
    for (int j = 0; j < 2; j++) {
      int rb = rb0 + 16 * j;
      int r = rb + rr;
      size_t eo = (size_t)(k0 + r) * DD + dc + 8 * g;
      char* lb = sm + (size_t)buf * 8192 + rb * 64;
      GLDS16(emb_h + eo, lb);
      GLDS16(emb_l + eo, lb + 16384);
    }
  };
  auto loadB = [&](f16x8* bh, f16x8* bl, int dc) {
#pragma unroll
    for (int s = 0; s < 2; s++) {
      bh[2 * s + 0] = *(const f16x8*)(pB0h + dc + 16 * s);
      bh[2 * s + 1] = *(const f16x8*)(pB1h + dc + 16 * s);
      bl[2 * s + 0] = *(const f16x8*)(pB0l + dc + 16 * s);
      bl[2 * s + 1] = *(const f16x8*)(pB1l + dc + 16 * s);
    }
  };

  f32x16 vzero;
#pragma unroll
  for (int i = 0; i < 16; i++) vzero[i] = 0.0f;

  float bestv[2];
  int   besti[2];
  bestv[0] = bestv[1] = 3.4e38f;
  besti[0] = besti[1] = 0;

  f16x8 B0h[4], B0l[4], B1h[4], B1l[4];

  stageE(0, 0, 0);
  loadB(B0h, B0l, 0);
  for (int kt = 0; kt < 4; kt++) {
    f32x16 acc00 = vzero, acc01 = vzero, acc10 = vzero, acc11 = vzero;
#pragma unroll
    for (int i = 0; i < 8; i++) {        // d-chunks of 32, fully unrolled
      const int dc = i * 32;
      const int cbuf = i & 1;
      __syncthreads();
      if (dc + 32 < DD) {
        stageE(cbuf ^ 1, kt, dc + 32);
        loadB(cbuf ? B0h : B1h, cbuf ? B0l : B1l, dc + 32);
      } else if (kt < 3) {
        stageE(cbuf ^ 1, kt + 1, 0);
        loadB(cbuf ? B0h : B1h, cbuf ? B0l : B1l, 0);
      }
      const _Float16* EHb = (const _Float16*)(sm + cbuf * 8192);
      const _Float16* ELb = (const _Float16*)(sm + 16384 + cbuf * 8192);
      const f16x8* bhc = cbuf ? B1h : B0h;
      const f16x8* blc = cbuf ? B1l : B0l;
#pragma unroll
      for (int s = 0; s < 2; s++) {
        const int pa = (2 * s + lh) ^ swz;   // swizzled 16B chunk (A reads)
        const int ar0 = (wm * 64 + lr) * 32 + pa * 8;
        const int ar1 = (wm * 64 + 32 + lr) * 32 + pa * 8;
        f16x8 ah0 = *(const f16x8*)(EHb + ar0);
        f16x8 ah1 = *(const f16x8*)(EHb + ar1);
        f16x8 al0 = *(const f16x8*)(ELb + ar0);
        f16x8 al1 = *(const f16x8*)(ELb + ar1);
        f16x8 bh0 = bhc[2 * s + 0], bh1 = bhc[2 * s + 1];
        f16x8 bl0 = blc[2 * s + 0], bl1 = blc[2 * s + 1];
        acc00 = MFMA16(ah0, bh0, acc00, 0, 0, 0);
        acc01 = MFMA16(ah0, bh1, acc01, 0, 0, 0);
        acc10 = MFMA16(ah1, bh0, acc10, 0, 0, 0);
        acc11 = MFMA16(ah1, bh1, acc11, 0, 0, 0);
        acc00 = MFMA16(ah0, bl0, acc00, 0, 0, 0);
        acc01 = MFMA16(ah0, bl1, acc01, 0, 0, 0);
        acc10 = MFMA16(ah1, bl0, acc10, 0, 0, 0);
        acc11 = MFMA16(ah1, bl1, acc11, 0, 0, 0);
        acc00 = MFMA16(al0, bh0, acc00, 0, 0, 0);
        acc01 = MFMA16(al0, bh1, acc01, 0, 0, 0);
        acc10 = MFMA16(al1, bh0, acc10, 0, 0, 0);
        acc11 = MFMA16(al1, bh1, acc11, 0, 0, 0);
      }
    }
#pragma unroll
    for (int mt = 0; mt < 2; mt++)
#pragma unroll
      for (int nt = 0; nt < 2; nt++) {
        const f32x16& a = (mt == 0) ? (nt == 0 ? acc00 : acc01)
                                    : (nt == 0 ? acc10 : acc11);
#pragma unroll
        for (int r = 0; r < 16; r++) {
          int kl = kt * 128 + wm * 64 + mt * 32 + (r & 3) + 8 * (r >> 2) + 4 * lh;
          float d2 = esqs[kl] - 2.0f * a[r];
          int kg = kbase + kl;
          if (d2 < bestv[nt] || (d2 == bestv[nt] && kg < besti[nt])) {
            bestv[nt] = d2; besti[nt] = kg;
          }
        }
      }
  }

#pragma unroll
  for (int nt = 0; nt < 2; nt++) {
    float ov = __shfl_xor(bestv[nt], 32, 64);
    int   oi = __shfl_xor(besti[nt], 32, 64);
    if (ov < bestv[nt] || (ov == bestv[nt] && oi < besti[nt])) {
      bestv[nt] = ov; besti[nt] = oi;
    }
  }
  float* pv = (float*)(sm + 34816);
  int*   pi = (int*)(sm + 35840);
  __syncthreads();
  if (lh == 0) {
#pragma unroll
    for (int nt = 0; nt < 2; nt++) {
      pv[(w * 2 + nt) * 32 + lr] = bestv[nt];
      pi[(w * 2 + nt) * 32 + lr] = besti[nt];
    }
  }
  __syncthreads();
  if (t < 128) {
    int wn2 = t >> 6, nt = (t >> 5) & 1, nl = t & 31;
    int i0 = ((2 * wn2 + 0) * 2 + nt) * 32 + nl;
    int i1 = ((2 * wn2 + 1) * 2 + nt) * 32 + nl;
    float v0 = pv[i0], v1 = pv[i1];
    int   j0 = pi[i0], j1 = pi[i1];
    if (v1 < v0 || (v1 == v0 && j1 < j0)) { v0 = v1; j0 = j1; }
    size_t o = ((size_t)ks * B_ + b) * NN_ + n0 + t;
    pval[o] = v0;
    pidx[o] = j0;
  }
}

// ---------- kernel 4: merge K-split partials -> mind ; histogram -> hist ----------
__global__ __launch_bounds__(256) void k_histm(const float* __restrict__ pval,
                                               const int* __restrict__ pidx,
                                               int* __restrict__ mind,
                                               int* __restrict__ hist) {
  __shared__ int h[KK];
  const int t = threadIdx.x;
#pragma unroll
  for (int i = 0; i < 8; i++) h[t + 256 * i] = 0;
  __syncthreads();
  const int base = blockIdx.x * 2048;
#pragma unroll
  for (int i = 0; i < 8; i++) {
    int g = base + i * 256 + t;
    float bv = pval[g];
    int   bi = pidx[g];
#pragma unroll
    for (int ks = 1; ks < KSPLIT; ks++) {
      float v = pval[(size_t)ks * NG + g];
      int  ii = pidx[(size_t)ks * NG + g];
      if (v < bv || (v == bv && ii < bi)) { bv = v; bi = ii; }
    }
    mind[g] = bi;
    atomicAdd(&h[bi], 1);
  }
  __syncthreads();
#pragma unroll
  for (int i = 0; i < 8; i++) {
    int v = h[t + 256 * i];
    if (v) atomicAdd(&hist[t + 256 * i], v);
  }
}

// ---------- kernel 5: exclusive prefix sum of hist -> cursor ; n_sum floats ----------
__global__ __launch_bounds__(256) void k_scan(const int* __restrict__ hist,
                                              int* __restrict__ cursor,
                                              float* __restrict__ nsumf) {
  __shared__ int ps[256];
  const int t = threadIdx.x;
  int c[8], s = 0;
#pragma unroll
  for (int e = 0; e < 8; e++) { c[e] = hist[8 * t + e]; s += c[e]; }
  ps[t] = s;
  __syncthreads();
  for (int off = 1; off < 256; off <<= 1) {
    int v = (t >= off) ? ps[t - off] : 0;
    __syncthreads();
    ps[t] += v;
    __syncthreads();
  }
  int run = ps[t] - s;
#pragma unroll
  for (int e = 0; e < 8; e++) {
    cursor[8 * t + e] = run;
    nsumf[8 * t + e] = (float)c[e];
    run += c[e];
  }
}

// ---------- kernel 6: scatter sample ids into sorted order (packed k<<15|g) ----------
__global__ __launch_bounds__(256) void k_pos(const int* __restrict__ mind,
                                             int* __restrict__ cursor,
                                             int* __restrict__ sortp) {
  int g = blockIdx.x * 256 + threadIdx.x;
  int k = mind[g];
  int p = atomicAdd(&cursor[k], 1);
  sortp[p] = (k << 15) | g;
}

// ---------- kernel 7: out[b,d,n] = emb[mind[b,n], d] ----------
__global__ __launch_bounds__(256) void k_out(const float* __restrict__ emb,
                                             const int* __restrict__ mind,
                                             float* __restrict__ out) {
  __shared__ __align__(16) float E[64][257];
  __shared__ int idxl[64];
  const int t = threadIdx.x;
  const int b  = blockIdx.y;
  const int n0 = blockIdx.x * 64;
  if (t < 64) idxl[t] = mind[(size_t)b * NN_ + n0 + t];
  __syncthreads();

  for (int i = 0; i < 16; i++) {
    int cid = t + 256 * i;
    int r = cid >> 6, q = cid & 63;
    float4 v = *(const float4*)&emb[(size_t)idxl[r] * DD + 4 * q];
    float* vp = (float*)&v;
    E[r][4 * q + 0] = vp[0];
    E[r][4 * q + 1] = vp[1];
    E[r][4 * q + 2] = vp[2];
    E[r][4 * q + 3] = vp[3];
  }
  __syncthreads();
  const int nq = t & 15, dg = t >> 4;
  float* outb = out + (size_t)b * DD * NN_ + n0;
#pragma unroll
  for (int i = 0; i < 16; i++) {
    int d = i * 16 + dg;
    float4 v = make_float4(E[4 * nq + 0][d], E[4 * nq + 1][d],
                           E[4 * nq + 2][d], E[4 * nq + 3][d]);
    *(float4*)&outb[(size_t)d * NN_ + 4 * nq] = v;
  }
}

// ---------- kernel 8: segment-sum over sorted runs -> z_sum ----------
__global__ __launch_bounds__(256) void k_zsum(const int* __restrict__ sortp,
                                              const _Float16* __restrict__ zeT_h,
                                              const _Float16* __restrict__ zeT_l,
                                              float* __restrict__ z_sum) {
  __shared__ int sg[256];
  const int t = threadIdx.x;
  const int w = t >> 6, lane = t & 63;
  sg[t] = sortp[blockIdx.x * 256 + t];
  __syncthreads();
  const int base = w * 64;
  float acc[4] = {0.f, 0.f, 0.f, 0.f};
  int cur = sg[base] >> 15;
  for (int j = 0; j < 64; j++) {
    int e = sg[base + j];
    int k = e >> 15, g = e & 32767;
    if (k != cur) {
      float* zs = &z_sum[(size_t)cur * DD + 4 * lane];
#pragma unroll
      for (int x = 0; x < 4; x++) { atomicAdd(&zs[x], acc[x]); acc[x] = 0.f; }
      cur = k;
    }
    f16x4 h = *(const f16x4*)&zeT_h[(size_t)g * DD + 4 * lane];
    f16x4 l = *(const f16x4*)&zeT_l[(size_t)g * DD + 4 * lane];
#pragma unroll
    for (int x = 0; x < 4; x++) acc[x] += (float)h[x] + (float)l[x];
  }
  float* zs = &z_sum[(size_t)cur * DD + 4 * lane];
#pragma unroll
  for (int x = 0; x < 4; x++) atomicAdd(&zs[x], acc[x]);
}

// ---------- kernel 9: EMA update ----------
__global__ __launch_bounds__(256) void k_ema(const float* __restrict__ ema_numer,
                                             const float* __restrict__ ema_denom,
                                             const float* __restrict__ z_sum,
                                             const float* __restrict__ nsumf,
                                             float* __restrict__ out_numer,
                                             float* __restrict__ out_denom) {
  const float G  = 0.99f;
  const float OG = 0.009999999776482582f;
  int i = blockIdx.x * 256 + threadIdx.x;
  if (i < KK * DD) {
    out_numer[i] = G * ema_numer[i] + OG * z_sum[i];
  } else {
    int j = i - KK * DD;
    if (j < KK) out_denom[j] = G * ema_denom[j] + OG * nsumf[j];
  }
}

extern "C" void kernel_launch(void* const* d_in, const int* in_sizes, int n_in,
                              void* d_out, int out_size, void* d_ws, size_t ws_size,
                              hipStream_t stream) {
  (void)in_sizes; (void)n_in; (void)out_size; (void)ws_size;
  const float* z         = (const float*)d_in[0];
  const float* W         = (const float*)d_in[1];
  const float* emb       = (const float*)d_in[2];
  const float* ema_numer = (const float*)d_in[3];
  const float* ema_denom = (const float*)d_in[4];

  float* out       = (float*)d_out;                        // (8,256,4096)
  float* out_numer = out + (size_t)B_ * DD * NN_;
  float* out_denom = out_numer + (size_t)KK * DD;

  const size_t ZET = (size_t)B_ * NN_ * DD;                // 8388608
  _Float16* zeT_h = (_Float16*)d_ws;                       // 16 MB
  _Float16* zeT_l = zeT_h + ZET;                           // 16 MB
  float* esq    = (float*)(zeT_l + ZET);                   // 2048
  float* zsum   = esq + KK;                                // 524288 (memset)
  int*   hist   = (int*)(zsum + (size_t)KK * DD);          // 2048   (memset, contiguous)
  int*   cursor = hist + KK;                               // 2048
  float* nsumf  = (float*)(cursor + KK);                   // 2048
  float* pval   = nsumf + KK;                              // 131072
  int*   pidx   = (int*)(pval + (size_t)KSPLIT * NG);      // 131072
  int*   mind   = pidx + (size_t)KSPLIT * NG;              // 32768
  int*   sortp  = mind + NG;                               // 32768
  _Float16* emb_h = (_Float16*)(sortp + NG);               // 524288 f16
  _Float16* emb_l = emb_h + (size_t)KK * DD;               // 524288 f16

  hipMemsetAsync(zsum, 0, (size_t)(KK * DD + KK) * sizeof(float), stream);

  k_esq<<<dim3(KK / 4), 256, 0, stream>>>(emb, esq, emb_h, emb_l);
  k_ze<<<dim3(NN_ / 128, DD / 128, B_), 256, 0, stream>>>(W, z, zeT_h, zeT_l);
  k_argmin<<<dim3(NN_ / 128, B_, KSPLIT), 256, 0, stream>>>(emb_h, emb_l, zeT_h, zeT_l,
                                                            esq, pval, pidx);
  k_histm<<<dim3(NG / 2048), 256, 0, stream>>>(pval, pidx, mind, hist);
  k_scan<<<dim3(1), 256, 0, stream>>>(hist, cursor, nsumf);
  k_pos<<<dim3(NG / 256), 256, 0, stream>>>(mind, cursor, sortp);
  k_out<<<dim3(NN_ / 64, B_), 256, 0, stream>>>(emb, mind, out);
  k_zsum<<<dim3(NG / 256), 256, 0, stream>>>(sortp, zeT_h, zeT_l, zsum);
  k_ema<<<dim3((KK * DD + KK) / 256), 256, 0, stream>>>(ema_numer, ema_denom, zsum, nsumf,
                                                        out_numer, out_denom);
}